// Round 1
// baseline (543.411 us; speedup 1.0000x reference)
//
#include <hip/hip_runtime.h>

typedef __bf16 bf16;
typedef __attribute__((ext_vector_type(8))) __bf16 bf16x8;
typedef __attribute__((ext_vector_type(4))) __bf16 bf16x4;
typedef __attribute__((ext_vector_type(4))) float f32x4;

constexpr int T_SEQ = 2048;
constexpr int DIM   = 2048;
constexpr int NH    = 32;
constexpr int NKV   = 8;
constexpr int HD    = 64;
constexpr int QKV_N = DIM + 2 * NKV * HD;   // 3072
constexpr int MROWS = 2 * T_SEQ;            // 4096 (B*T)

// ---------------- cast f32 -> bf16 ----------------
__global__ void cast_kernel(const float* __restrict__ in, bf16* __restrict__ out, int n) {
  int stride = gridDim.x * blockDim.x * 4;
  for (int i = (blockIdx.x * blockDim.x + threadIdx.x) * 4; i < n; i += stride) {
    float4 v = *(const float4*)(in + i);
    bf16x4 o = { (bf16)v.x, (bf16)v.y, (bf16)v.z, (bf16)v.w };
    *(bf16x4*)(out + i) = o;
  }
}

// ---------------- GEMM: C[m][n] = sum_k A[m][k] * W[n][k] ----------------
// 128x128 tile, BK=64, 4 waves (2x2 of 64x64), global_load_lds staging.
template <typename OutT>
__global__ __launch_bounds__(256) void gemm_bt(const bf16* __restrict__ A,
                                               const bf16* __restrict__ W,
                                               OutT* __restrict__ C,
                                               int M, int N, int K) {
  constexpr int BM = 128, BN = 128, BK = 64;
  __shared__ __attribute__((aligned(16))) bf16 Ab[BM * BK];
  __shared__ __attribute__((aligned(16))) bf16 Bb[BN * BK];
  const int tid  = threadIdx.x;
  const int lane = tid & 63, wave = tid >> 6;
  const int bm = blockIdx.x * BM, bn = blockIdx.y * BN;
  const int wm = (wave >> 1) * 64, wn = (wave & 1) * 64;
  const int l15 = lane & 15, l4 = lane >> 4;

  f32x4 acc[4][4] = {};

  for (int k0 = 0; k0 < K; k0 += BK) {
    // stage A,B tiles: each 128x64 bf16 = 16KB; 4 issues x 256 thr x 16B
    for (int i = 0; i < 4; ++i) {
      int chunk = i * 256 + tid;            // 8 bf16 per chunk, linear in tid
      int r = chunk >> 3, c = (chunk & 7) << 3;
      __builtin_amdgcn_global_load_lds(
          (const __attribute__((address_space(1))) unsigned int*)(A + (size_t)(bm + r) * K + k0 + c),
          (__attribute__((address_space(3))) unsigned int*)(Ab + chunk * 8), 16, 0, 0);
      __builtin_amdgcn_global_load_lds(
          (const __attribute__((address_space(1))) unsigned int*)(W + (size_t)(bn + r) * K + k0 + c),
          (__attribute__((address_space(3))) unsigned int*)(Bb + chunk * 8), 16, 0, 0);
    }
    __syncthreads();
    #pragma unroll
    for (int kk = 0; kk < 2; ++kk) {
      const int co = kk * 32 + l4 * 8;
      bf16x8 af[4], bfr[4];
      #pragma unroll
      for (int mi = 0; mi < 4; ++mi)
        af[mi] = *(const bf16x8*)(Ab + (wm + mi * 16 + l15) * BK + co);
      #pragma unroll
      for (int ni = 0; ni < 4; ++ni)
        bfr[ni] = *(const bf16x8*)(Bb + (wn + ni * 16 + l15) * BK + co);
      #pragma unroll
      for (int mi = 0; mi < 4; ++mi)
        #pragma unroll
        for (int ni = 0; ni < 4; ++ni)
          acc[mi][ni] = __builtin_amdgcn_mfma_f32_16x16x32_bf16(af[mi], bfr[ni], acc[mi][ni], 0, 0, 0);
    }
    __syncthreads();
  }

  #pragma unroll
  for (int mi = 0; mi < 4; ++mi)
    #pragma unroll
    for (int ni = 0; ni < 4; ++ni) {
      size_t row = (size_t)bm + wm + mi * 16 + l4 * 4;
      int col = bn + wn + ni * 16 + l15;
      #pragma unroll
      for (int r = 0; r < 4; ++r)
        C[(row + r) * N + col] = (OutT)acc[mi][ni][r];
    }
}

// ---------------- RoPE on q (cols 0..2047) and k (cols 2048..2559) ----------------
__global__ void rope_kernel(bf16* __restrict__ qkv, const float* __restrict__ cs,
                            const float* __restrict__ sn) {
  int pid = blockIdx.x * blockDim.x + threadIdx.x;   // MROWS * 1280 total
  int m = pid / 1280;
  int p = pid - m * 1280;
  int t = m & (T_SEQ - 1);
  int i, col;
  if (p < 1024) { int hh = p >> 5; i = p & 31; col = hh * 64 + 2 * i; }
  else          { int p2 = p - 1024; int hh = p2 >> 5; i = p2 & 31; col = DIM + hh * 64 + 2 * i; }
  float c = cs[t * 32 + i], s = sn[t * 32 + i];
  bf16* ptr = qkv + (size_t)m * QKV_N + col;
  float a = (float)ptr[0], b = (float)ptr[1];
  ptr[0] = (bf16)(a * c - b * s);
  ptr[1] = (bf16)(a * s + b * c);
}

// ---------------- Flash attention, causal GQA ----------------
// grid (T/64, NH, B); 4 waves, each wave owns 16 q rows; KV tile = 64.
__global__ __launch_bounds__(256) void attn_kernel(const bf16* __restrict__ qkv,
                                                   bf16* __restrict__ y) {
  const int qt = blockIdx.x, h = blockIdx.y, b = blockIdx.z;
  const int g = h >> 2;  // kv head
  const int tid = threadIdx.x, lane = tid & 63, wave = tid >> 6;
  const int l15 = lane & 15, l4 = lane >> 4;
  __shared__ __attribute__((aligned(16))) bf16 Kb[64 * 64];
  __shared__ __attribute__((aligned(16))) bf16 VT[64 * 64];
  __shared__ __attribute__((aligned(16))) bf16 Pb[4][16 * 64];

  // Q fragments (A operand): rows wave*16 .. +15, row = lane&15
  bf16x8 qf[2];
  {
    size_t qrow = (size_t)b * T_SEQ + qt * 64 + wave * 16 + l15;
    const bf16* qp = qkv + qrow * QKV_N + h * HD + l4 * 8;
    qf[0] = *(const bf16x8*)(qp);
    qf[1] = *(const bf16x8*)(qp + 32);
  }

  f32x4 oacc[4] = {};
  float m_run[4], l_run[4];
  #pragma unroll
  for (int r = 0; r < 4; ++r) { m_run[r] = -INFINITY; l_run[r] = 0.f; }

  const int qg0 = qt * 64 + wave * 16 + l4 * 4;   // + r

  for (int kt = 0; kt <= qt; ++kt) {
    __syncthreads();   // all waves done reading previous K/V tile
    // stage K (linear) via global_load_lds: 64x64 bf16 = 8KB, 2 issues
    for (int i = 0; i < 2; ++i) {
      int chunk = i * 256 + tid;
      int r = chunk >> 3, c = (chunk & 7) << 3;
      __builtin_amdgcn_global_load_lds(
          (const __attribute__((address_space(1))) unsigned int*)
              (qkv + ((size_t)b * T_SEQ + kt * 64 + r) * QKV_N + DIM + g * HD + c),
          (__attribute__((address_space(3))) unsigned int*)(Kb + chunk * 8), 16, 0, 0);
    }
    // stage V transposed (VT[d][kv]) via register round-trip
    for (int i = 0; i < 2; ++i) {
      int chunk = i * 256 + tid;
      int r = chunk >> 3, c = (chunk & 7) << 3;
      bf16x8 v = *(const bf16x8*)
          (qkv + ((size_t)b * T_SEQ + kt * 64 + r) * QKV_N + DIM + NKV * HD + g * HD + c);
      #pragma unroll
      for (int j = 0; j < 8; ++j) VT[(c + j) * 64 + r] = v[j];
    }
    __syncthreads();

    // S = Q K^T  (16q x 64kv per wave)
    f32x4 sv[4];
    #pragma unroll
    for (int nt = 0; nt < 4; ++nt) {
      f32x4 z = {};
      #pragma unroll
      for (int kk = 0; kk < 2; ++kk) {
        bf16x8 kf = *(const bf16x8*)(Kb + (nt * 16 + l15) * 64 + kk * 32 + l4 * 8);
        z = __builtin_amdgcn_mfma_f32_16x16x32_bf16(qf[kk], kf, z, 0, 0, 0);
      }
      sv[nt] = z;
    }

    // scale + causal mask: lane holds S[row=l4*4+r][col=nt*16+l15]
    float s[4][4];
    #pragma unroll
    for (int nt = 0; nt < 4; ++nt) {
      int kg = kt * 64 + nt * 16 + l15;
      #pragma unroll
      for (int r = 0; r < 4; ++r) {
        float v = sv[nt][r] * 0.125f;
        s[nt][r] = (kg > qg0 + r) ? -INFINITY : v;
      }
    }

    // online softmax: row reduce within 16-lane group
    #pragma unroll
    for (int r = 0; r < 4; ++r) {
      float v = fmaxf(fmaxf(s[0][r], s[1][r]), fmaxf(s[2][r], s[3][r]));
      v = fmaxf(v, __shfl_xor(v, 1));
      v = fmaxf(v, __shfl_xor(v, 2));
      v = fmaxf(v, __shfl_xor(v, 4));
      v = fmaxf(v, __shfl_xor(v, 8));
      float mnew = fmaxf(m_run[r], v);
      float alpha = __expf(m_run[r] - mnew);
      m_run[r] = mnew;
      l_run[r] *= alpha;
      oacc[0][r] *= alpha; oacc[1][r] *= alpha; oacc[2][r] *= alpha; oacc[3][r] *= alpha;
    }

    // P = exp(s - m) -> per-wave LDS (bf16), accumulate row sums
    bf16* pb = &Pb[wave][0];
    float psum[4] = {0.f, 0.f, 0.f, 0.f};
    #pragma unroll
    for (int nt = 0; nt < 4; ++nt)
      #pragma unroll
      for (int r = 0; r < 4; ++r) {
        float p = __expf(s[nt][r] - m_run[r]);
        psum[r] += p;
        pb[(l4 * 4 + r) * 64 + nt * 16 + l15] = (bf16)p;
      }
    #pragma unroll
    for (int r = 0; r < 4; ++r) {
      float v = psum[r];
      v += __shfl_xor(v, 1); v += __shfl_xor(v, 2);
      v += __shfl_xor(v, 4); v += __shfl_xor(v, 8);
      l_run[r] += v;
    }

    // O += P @ V   (A = P from LDS, B = V via VT rows)
    #pragma unroll
    for (int kk = 0; kk < 2; ++kk) {
      bf16x8 pf = *(const bf16x8*)(pb + l15 * 64 + kk * 32 + l4 * 8);
      #pragma unroll
      for (int dt = 0; dt < 4; ++dt) {
        bf16x8 vf = *(const bf16x8*)(VT + (dt * 16 + l15) * 64 + kk * 32 + l4 * 8);
        oacc[dt] = __builtin_amdgcn_mfma_f32_16x16x32_bf16(pf, vf, oacc[dt], 0, 0, 0);
      }
    }
  }

  // epilogue: y[b,t,h,d] = O / l
  #pragma unroll
  for (int dt = 0; dt < 4; ++dt)
    #pragma unroll
    for (int r = 0; r < 4; ++r) {
      float v = oacc[dt][r] / l_run[r];
      y[((size_t)b * T_SEQ + qt * 64 + wave * 16 + l4 * 4 + r) * DIM + h * HD + dt * 16 + l15] = (bf16)v;
    }
}

// ---------------- launch ----------------
extern "C" void kernel_launch(void* const* d_in, const int* in_sizes, int n_in,
                              void* d_out, int out_size, void* d_ws, size_t ws_size,
                              hipStream_t stream) {
  const float* x    = (const float*)d_in[0];
  const float* cosb = (const float*)d_in[1];
  const float* sinb = (const float*)d_in[2];
  const float* wq   = (const float*)d_in[3];
  const float* wk   = (const float*)d_in[4];
  const float* wv   = (const float*)d_in[5];
  const float* wo   = (const float*)d_in[6];
  float* out = (float*)d_out;

  bf16* xb   = (bf16*)d_ws;                           // 4096*2048
  bf16* wqkv = xb + (size_t)MROWS * DIM;              // 3072*2048
  bf16* wob  = wqkv + (size_t)QKV_N * DIM;            // 2048*2048
  bf16* qkv  = wob + (size_t)DIM * DIM;               // 4096*3072
  bf16* y    = qkv + (size_t)MROWS * QKV_N;           // 4096*2048

  cast_kernel<<<2048, 256, 0, stream>>>(x, xb, MROWS * DIM);
  cast_kernel<<<2048, 256, 0, stream>>>(wq, wqkv, DIM * DIM);
  cast_kernel<<<512, 256, 0, stream>>>(wk, wqkv + (size_t)DIM * DIM, NKV * HD * DIM);
  cast_kernel<<<512, 256, 0, stream>>>(wv, wqkv + (size_t)(DIM + NKV * HD) * DIM, NKV * HD * DIM);
  cast_kernel<<<2048, 256, 0, stream>>>(wo, wob, DIM * DIM);

  // QKV projection: M=4096, N=3072, K=2048
  gemm_bt<bf16><<<dim3(MROWS / 128, QKV_N / 128), 256, 0, stream>>>(xb, wqkv, qkv, MROWS, QKV_N, DIM);

  // RoPE on q,k
  rope_kernel<<<(MROWS * 1280) / 256, 256, 0, stream>>>(qkv, cosb, sinb);

  // attention
  attn_kernel<<<dim3(T_SEQ / 64, NH, 2), 256, 0, stream>>>(qkv, y);

  // output projection: M=4096, N=2048, K=2048, f32 out
  gemm_bt<float><<<dim3(MROWS / 128, DIM / 128), 256, 0, stream>>>(y, wob, out, MROWS, DIM, DIM);
}

// Round 2
// 390.362 us; speedup vs baseline: 1.3921x; 1.3921x over previous
//
#include <hip/hip_runtime.h>

typedef __bf16 bf16;
typedef __attribute__((ext_vector_type(8))) __bf16 bf16x8;
typedef __attribute__((ext_vector_type(4))) __bf16 bf16x4;
typedef __attribute__((ext_vector_type(4))) float f32x4;

constexpr int T_SEQ = 2048;
constexpr int DIM   = 2048;
constexpr int NH    = 32;
constexpr int NKV   = 8;
constexpr int HD    = 64;
constexpr int QKV_N = DIM + 2 * NKV * HD;   // 3072
constexpr int MROWS = 2 * T_SEQ;            // 4096 (B*T)

// ---------------- cast f32 -> bf16 ----------------
__global__ void cast_kernel(const float* __restrict__ in, bf16* __restrict__ out, int n) {
  int stride = gridDim.x * blockDim.x * 4;
  for (int i = (blockIdx.x * blockDim.x + threadIdx.x) * 4; i < n; i += stride) {
    float4 v = *(const float4*)(in + i);
    bf16x4 o = { (bf16)v.x, (bf16)v.y, (bf16)v.z, (bf16)v.w };
    *(bf16x4*)(out + i) = o;
  }
}

// ---------------- GEMM: C[m][n] = sum_k A[m][k] * W[n][k] ----------------
template <typename OutT>
__global__ __launch_bounds__(256) void gemm_bt(const bf16* __restrict__ A,
                                               const bf16* __restrict__ W,
                                               OutT* __restrict__ C,
                                               int M, int N, int K) {
  constexpr int BM = 128, BN = 128, BK = 64;
  __shared__ __attribute__((aligned(16))) bf16 Ab[BM * BK];
  __shared__ __attribute__((aligned(16))) bf16 Bb[BN * BK];
  const int tid  = threadIdx.x;
  const int lane = tid & 63, wave = tid >> 6;
  const int bm = blockIdx.x * BM, bn = blockIdx.y * BN;
  const int wm = (wave >> 1) * 64, wn = (wave & 1) * 64;
  const int l15 = lane & 15, l4 = lane >> 4;

  f32x4 acc[4][4] = {};

  for (int k0 = 0; k0 < K; k0 += BK) {
    for (int i = 0; i < 4; ++i) {
      int chunk = i * 256 + tid;
      int r = chunk >> 3, c = (chunk & 7) << 3;
      __builtin_amdgcn_global_load_lds(
          (const __attribute__((address_space(1))) unsigned int*)(A + (size_t)(bm + r) * K + k0 + c),
          (__attribute__((address_space(3))) unsigned int*)(Ab + chunk * 8), 16, 0, 0);
      __builtin_amdgcn_global_load_lds(
          (const __attribute__((address_space(1))) unsigned int*)(W + (size_t)(bn + r) * K + k0 + c),
          (__attribute__((address_space(3))) unsigned int*)(Bb + chunk * 8), 16, 0, 0);
    }
    __syncthreads();
    #pragma unroll
    for (int kk = 0; kk < 2; ++kk) {
      const int co = kk * 32 + l4 * 8;
      bf16x8 af[4], bfr[4];
      #pragma unroll
      for (int mi = 0; mi < 4; ++mi)
        af[mi] = *(const bf16x8*)(Ab + (wm + mi * 16 + l15) * BK + co);
      #pragma unroll
      for (int ni = 0; ni < 4; ++ni)
        bfr[ni] = *(const bf16x8*)(Bb + (wn + ni * 16 + l15) * BK + co);
      #pragma unroll
      for (int mi = 0; mi < 4; ++mi)
        #pragma unroll
        for (int ni = 0; ni < 4; ++ni)
          acc[mi][ni] = __builtin_amdgcn_mfma_f32_16x16x32_bf16(af[mi], bfr[ni], acc[mi][ni], 0, 0, 0);
    }
    __syncthreads();
  }

  #pragma unroll
  for (int mi = 0; mi < 4; ++mi)
    #pragma unroll
    for (int ni = 0; ni < 4; ++ni) {
      size_t row = (size_t)bm + wm + mi * 16 + l4 * 4;
      int col = bn + wn + ni * 16 + l15;
      #pragma unroll
      for (int r = 0; r < 4; ++r)
        C[(row + r) * N + col] = (OutT)acc[mi][ni][r];
    }
}

// ---------------- RoPE, vectorized: 16 bf16 (8 pairs) per thread ----------------
__global__ void rope_kernel(bf16* __restrict__ qkv, const float* __restrict__ cs,
                            const float* __restrict__ sn) {
  int idx = blockIdx.x * blockDim.x + threadIdx.x;   // MROWS*160 total
  int m = idx / 160;
  int ch = idx - m * 160;
  int t = m & (T_SEQ - 1);
  int col, c;
  if (ch < 128) { int hh = ch >> 2; c = ch & 3; col = hh * 64 + c * 16; }
  else          { int ch2 = ch - 128; int hh = ch2 >> 2; c = ch2 & 3; col = DIM + hh * 64 + c * 16; }
  bf16* ptr = qkv + (size_t)m * QKV_N + col;
  bf16x8 v0 = *(bf16x8*)ptr, v1 = *(bf16x8*)(ptr + 8);
  const float* cp = cs + t * 32 + c * 8;
  const float* sp = sn + t * 32 + c * 8;
  float4 c0 = *(const float4*)cp, c1 = *(const float4*)(cp + 4);
  float4 s0 = *(const float4*)sp, s1 = *(const float4*)(sp + 4);
  float cc[8] = {c0.x, c0.y, c0.z, c0.w, c1.x, c1.y, c1.z, c1.w};
  float ss[8] = {s0.x, s0.y, s0.z, s0.w, s1.x, s1.y, s1.z, s1.w};
  bf16x8 o0, o1;
  #pragma unroll
  for (int j = 0; j < 4; ++j) {
    float a = (float)v0[2 * j], b = (float)v0[2 * j + 1];
    o0[2 * j]     = (bf16)(a * cc[j] - b * ss[j]);
    o0[2 * j + 1] = (bf16)(a * ss[j] + b * cc[j]);
  }
  #pragma unroll
  for (int j = 0; j < 4; ++j) {
    float a = (float)v1[2 * j], b = (float)v1[2 * j + 1];
    o1[2 * j]     = (bf16)(a * cc[4 + j] - b * ss[4 + j]);
    o1[2 * j + 1] = (bf16)(a * ss[4 + j] + b * cc[4 + j]);
  }
  *(bf16x8*)ptr = o0;
  *(bf16x8*)(ptr + 8) = o1;
}

// ---------------- Flash attention, causal GQA ----------------
// grid (T/128, NH, B); 8 waves x 16 q-rows = 128 q rows per block; KV tile = 64.
// All LDS tiles XOR-swizzled: byte ^= ((row&7)<<4) within 128B rows.
__global__ __launch_bounds__(512) void attn_kernel(const bf16* __restrict__ qkv,
                                                   bf16* __restrict__ y) {
  const int qb = blockIdx.x, h = blockIdx.y, b = blockIdx.z;
  const int g = h >> 2;  // kv head
  const int tid = threadIdx.x, lane = tid & 63, wave = tid >> 6;
  const int l15 = lane & 15, l4 = lane >> 4;
  __shared__ __attribute__((aligned(16))) bf16 Kb[64 * 64];      // [kv][d], swizzled
  __shared__ __attribute__((aligned(16))) bf16 VT[64 * 64];      // [d][kv], swizzled
  __shared__ __attribute__((aligned(16))) bf16 Pb[8][16 * 64];   // per-wave [q][kv], swizzled

  // Q fragments: rows qb*128 + wave*16 + l15
  bf16x8 qf[2];
  {
    size_t qrow = (size_t)b * T_SEQ + qb * 128 + wave * 16 + l15;
    const bf16* qp = qkv + qrow * QKV_N + h * HD + l4 * 8;
    qf[0] = *(const bf16x8*)(qp);
    qf[1] = *(const bf16x8*)(qp + 32);
  }

  f32x4 oacc[4] = {};
  float m_run[4], l_run[4];
  #pragma unroll
  for (int r = 0; r < 4; ++r) { m_run[r] = -INFINITY; l_run[r] = 0.f; }

  const int qg0 = qb * 128 + wave * 16 + l4 * 4;            // +r = global q row
  const int wave_qmax = qb * 128 + wave * 16 + 15;
  const int nkt = (qb + 1) * 2;

  for (int kt = 0; kt < nkt; ++kt) {
    __syncthreads();   // previous tile fully consumed
    // ---- stage K via global_load_lds, source pre-swizzled ----
    {
      int r = tid >> 3, c8 = (tid & 7) << 3;
      int csrc = c8 ^ ((r & 7) << 3);
      __builtin_amdgcn_global_load_lds(
          (const __attribute__((address_space(1))) unsigned int*)
              (qkv + ((size_t)b * T_SEQ + kt * 64 + r) * QKV_N + DIM + g * HD + csrc),
          (__attribute__((address_space(3))) unsigned int*)(Kb + tid * 8), 16, 0, 0);
    }
    // ---- stage V transposed: column-gather from global, swizzled 16B LDS writes ----
    {
      int d = tid & 63, ks = tid >> 6;
      const bf16* vp = qkv + ((size_t)b * T_SEQ + kt * 64 + ks * 8) * QKV_N
                           + DIM + NKV * HD + g * HD + d;
      bf16x8 col;
      #pragma unroll
      for (int j = 0; j < 8; ++j) col[j] = vp[(size_t)j * QKV_N];
      *(bf16x8*)((char*)VT + ((d * 128 + ks * 16) ^ ((d & 7) << 4))) = col;
    }
    __syncthreads();

    if (kt * 64 <= wave_qmax) {   // skip fully-masked tiles (also avoids -inf NaN)
      // ---- S = Q K^T ----
      f32x4 sv[4];
      #pragma unroll
      for (int nt = 0; nt < 4; ++nt) {
        f32x4 z = {};
        #pragma unroll
        for (int kk = 0; kk < 2; ++kk) {
          bf16x8 kf = *(const bf16x8*)((char*)Kb +
              (((nt * 16 + l15) * 128 + (kk * 32 + l4 * 8) * 2) ^ ((l15 & 7) << 4)));
          z = __builtin_amdgcn_mfma_f32_16x16x32_bf16(qf[kk], kf, z, 0, 0, 0);
        }
        sv[nt] = z;
      }

      // ---- scale + causal mask ----
      float s[4][4];
      #pragma unroll
      for (int nt = 0; nt < 4; ++nt) {
        int kg = kt * 64 + nt * 16 + l15;
        #pragma unroll
        for (int r = 0; r < 4; ++r) {
          float v = sv[nt][r] * 0.125f;
          s[nt][r] = (kg > qg0 + r) ? -INFINITY : v;
        }
      }

      // ---- online softmax (row spans 16 lanes) ----
      #pragma unroll
      for (int r = 0; r < 4; ++r) {
        float v = fmaxf(fmaxf(s[0][r], s[1][r]), fmaxf(s[2][r], s[3][r]));
        v = fmaxf(v, __shfl_xor(v, 1));
        v = fmaxf(v, __shfl_xor(v, 2));
        v = fmaxf(v, __shfl_xor(v, 4));
        v = fmaxf(v, __shfl_xor(v, 8));
        float mnew = fmaxf(m_run[r], v);
        float alpha = __expf(m_run[r] - mnew);
        m_run[r] = mnew;
        l_run[r] *= alpha;
        oacc[0][r] *= alpha; oacc[1][r] *= alpha; oacc[2][r] *= alpha; oacc[3][r] *= alpha;
      }

      // ---- P = exp(s-m) -> per-wave swizzled LDS; row sums ----
      bf16* pb = &Pb[wave][0];
      float psum[4] = {0.f, 0.f, 0.f, 0.f};
      #pragma unroll
      for (int nt = 0; nt < 4; ++nt)
        #pragma unroll
        for (int r = 0; r < 4; ++r) {
          float p = __expf(s[nt][r] - m_run[r]);
          psum[r] += p;
          int row = l4 * 4 + r;
          *(bf16*)((char*)pb + ((row * 128 + (nt * 16 + l15) * 2) ^ ((row & 7) << 4))) = (bf16)p;
        }
      #pragma unroll
      for (int r = 0; r < 4; ++r) {
        float v = psum[r];
        v += __shfl_xor(v, 1); v += __shfl_xor(v, 2);
        v += __shfl_xor(v, 4); v += __shfl_xor(v, 8);
        l_run[r] += v;
      }

      // ---- O += P @ V ----
      #pragma unroll
      for (int kk = 0; kk < 2; ++kk) {
        bf16x8 pf = *(const bf16x8*)((char*)pb +
            ((l15 * 128 + (kk * 32 + l4 * 8) * 2) ^ ((l15 & 7) << 4)));
        #pragma unroll
        for (int dt = 0; dt < 4; ++dt) {
          bf16x8 vf = *(const bf16x8*)((char*)VT +
              (((dt * 16 + l15) * 128 + (kk * 32 + l4 * 8) * 2) ^ ((l15 & 7) << 4)));
          oacc[dt] = __builtin_amdgcn_mfma_f32_16x16x32_bf16(pf, vf, oacc[dt], 0, 0, 0);
        }
      }
    }
  }

  // ---- epilogue ----
  #pragma unroll
  for (int dt = 0; dt < 4; ++dt)
    #pragma unroll
    for (int r = 0; r < 4; ++r) {
      float v = oacc[dt][r] / l_run[r];
      y[((size_t)b * T_SEQ + qb * 128 + wave * 16 + l4 * 4 + r) * DIM + h * HD + dt * 16 + l15] = (bf16)v;
    }
}

// ---------------- launch ----------------
extern "C" void kernel_launch(void* const* d_in, const int* in_sizes, int n_in,
                              void* d_out, int out_size, void* d_ws, size_t ws_size,
                              hipStream_t stream) {
  const float* x    = (const float*)d_in[0];
  const float* cosb = (const float*)d_in[1];
  const float* sinb = (const float*)d_in[2];
  const float* wq   = (const float*)d_in[3];
  const float* wk   = (const float*)d_in[4];
  const float* wv   = (const float*)d_in[5];
  const float* wo   = (const float*)d_in[6];
  float* out = (float*)d_out;

  bf16* xb   = (bf16*)d_ws;                           // 4096*2048
  bf16* wqkv = xb + (size_t)MROWS * DIM;              // 3072*2048
  bf16* wob  = wqkv + (size_t)QKV_N * DIM;            // 2048*2048
  bf16* qkv  = wob + (size_t)DIM * DIM;               // 4096*3072
  bf16* y    = qkv + (size_t)MROWS * QKV_N;           // 4096*2048

  cast_kernel<<<2048, 256, 0, stream>>>(x, xb, MROWS * DIM);
  cast_kernel<<<2048, 256, 0, stream>>>(wq, wqkv, DIM * DIM);
  cast_kernel<<<512, 256, 0, stream>>>(wk, wqkv + (size_t)DIM * DIM, NKV * HD * DIM);
  cast_kernel<<<512, 256, 0, stream>>>(wv, wqkv + (size_t)(DIM + NKV * HD) * DIM, NKV * HD * DIM);
  cast_kernel<<<2048, 256, 0, stream>>>(wo, wob, DIM * DIM);

  // QKV projection: M=4096, N=3072, K=2048
  gemm_bt<bf16><<<dim3(MROWS / 128, QKV_N / 128), 256, 0, stream>>>(xb, wqkv, qkv, MROWS, QKV_N, DIM);

  // RoPE on q,k
  rope_kernel<<<(MROWS * 160) / 256, 256, 0, stream>>>(qkv, cosb, sinb);

  // attention
  attn_kernel<<<dim3(T_SEQ / 128, NH, 2), 512, 0, stream>>>(qkv, y);

  // output projection: M=4096, N=2048, K=2048, f32 out
  gemm_bt<float><<<dim3(MROWS / 128, DIM / 128), 256, 0, stream>>>(y, wob, out, MROWS, DIM, DIM);
}

// Round 4
// 327.648 us; speedup vs baseline: 1.6585x; 1.1914x over previous
//
#include <hip/hip_runtime.h>

typedef __bf16 bf16;
typedef __attribute__((ext_vector_type(8))) __bf16 bf16x8;
typedef __attribute__((ext_vector_type(4))) __bf16 bf16x4;
typedef __attribute__((ext_vector_type(4))) float f32x4;

constexpr int T_SEQ = 2048;
constexpr int DIM   = 2048;
constexpr int NH    = 32;
constexpr int NKV   = 8;
constexpr int HD    = 64;
constexpr int QKV_N = DIM + 2 * NKV * HD;   // 3072
constexpr int MROWS = 2 * T_SEQ;            // 4096 (B*T)

// ---------------- cast f32 -> bf16 ----------------
__global__ void cast_kernel(const float* __restrict__ in, bf16* __restrict__ out, int n) {
  int stride = gridDim.x * blockDim.x * 4;
  for (int i = (blockIdx.x * blockDim.x + threadIdx.x) * 4; i < n; i += stride) {
    float4 v = *(const float4*)(in + i);
    bf16x4 o = { (bf16)v.x, (bf16)v.y, (bf16)v.z, (bf16)v.w };
    *(bf16x4*)(out + i) = o;
  }
}

// ---------------- GEMM: C[m][n] = sum_k A[m][k] * W[n][k] ----------------
template <typename OutT>
__global__ __launch_bounds__(256) void gemm_bt(const bf16* __restrict__ A,
                                               const bf16* __restrict__ W,
                                               OutT* __restrict__ C,
                                               int M, int N, int K) {
  constexpr int BM = 128, BN = 128, BK = 64;
  __shared__ __attribute__((aligned(16))) bf16 Ab[BM * BK];
  __shared__ __attribute__((aligned(16))) bf16 Bb[BN * BK];
  const int tid  = threadIdx.x;
  const int lane = tid & 63, wave = tid >> 6;
  const int bm = blockIdx.x * BM, bn = blockIdx.y * BN;
  const int wm = (wave >> 1) * 64, wn = (wave & 1) * 64;
  const int l15 = lane & 15, l4 = lane >> 4;

  f32x4 acc[4][4] = {};

  for (int k0 = 0; k0 < K; k0 += BK) {
    for (int i = 0; i < 4; ++i) {
      int chunk = i * 256 + tid;
      int r = chunk >> 3, c = (chunk & 7) << 3;
      __builtin_amdgcn_global_load_lds(
          (const __attribute__((address_space(1))) unsigned int*)(A + (size_t)(bm + r) * K + k0 + c),
          (__attribute__((address_space(3))) unsigned int*)(Ab + chunk * 8), 16, 0, 0);
      __builtin_amdgcn_global_load_lds(
          (const __attribute__((address_space(1))) unsigned int*)(W + (size_t)(bn + r) * K + k0 + c),
          (__attribute__((address_space(3))) unsigned int*)(Bb + chunk * 8), 16, 0, 0);
    }
    __syncthreads();
    #pragma unroll
    for (int kk = 0; kk < 2; ++kk) {
      const int co = kk * 32 + l4 * 8;
      bf16x8 af[4], bfr[4];
      #pragma unroll
      for (int mi = 0; mi < 4; ++mi)
        af[mi] = *(const bf16x8*)(Ab + (wm + mi * 16 + l15) * BK + co);
      #pragma unroll
      for (int ni = 0; ni < 4; ++ni)
        bfr[ni] = *(const bf16x8*)(Bb + (wn + ni * 16 + l15) * BK + co);
      #pragma unroll
      for (int mi = 0; mi < 4; ++mi)
        #pragma unroll
        for (int ni = 0; ni < 4; ++ni)
          acc[mi][ni] = __builtin_amdgcn_mfma_f32_16x16x32_bf16(af[mi], bfr[ni], acc[mi][ni], 0, 0, 0);
    }
    __syncthreads();
  }

  #pragma unroll
  for (int mi = 0; mi < 4; ++mi)
    #pragma unroll
    for (int ni = 0; ni < 4; ++ni) {
      size_t row = (size_t)bm + wm + mi * 16 + l4 * 4;
      int col = bn + wn + ni * 16 + l15;
      #pragma unroll
      for (int r = 0; r < 4; ++r)
        C[(row + r) * N + col] = (OutT)acc[mi][ni][r];
    }
}

// ---------------- RoPE, vectorized: 16 bf16 (8 pairs) per thread ----------------
__global__ void rope_kernel(bf16* __restrict__ qkv, const float* __restrict__ cs,
                            const float* __restrict__ sn) {
  int idx = blockIdx.x * blockDim.x + threadIdx.x;   // MROWS*160 total
  int m = idx / 160;
  int ch = idx - m * 160;
  int t = m & (T_SEQ - 1);
  int col, c;
  if (ch < 128) { int hh = ch >> 2; c = ch & 3; col = hh * 64 + c * 16; }
  else          { int ch2 = ch - 128; int hh = ch2 >> 2; c = ch2 & 3; col = DIM + hh * 64 + c * 16; }
  bf16* ptr = qkv + (size_t)m * QKV_N + col;
  bf16x8 v0 = *(bf16x8*)ptr, v1 = *(bf16x8*)(ptr + 8);
  const float* cp = cs + t * 32 + c * 8;
  const float* sp = sn + t * 32 + c * 8;
  float4 c0 = *(const float4*)cp, c1 = *(const float4*)(cp + 4);
  float4 s0 = *(const float4*)sp, s1 = *(const float4*)(sp + 4);
  float cc[8] = {c0.x, c0.y, c0.z, c0.w, c1.x, c1.y, c1.z, c1.w};
  float ss[8] = {s0.x, s0.y, s0.z, s0.w, s1.x, s1.y, s1.z, s1.w};
  bf16x8 o0, o1;
  #pragma unroll
  for (int j = 0; j < 4; ++j) {
    float a = (float)v0[2 * j], b = (float)v0[2 * j + 1];
    o0[2 * j]     = (bf16)(a * cc[j] - b * ss[j]);
    o0[2 * j + 1] = (bf16)(a * ss[j] + b * cc[j]);
  }
  #pragma unroll
  for (int j = 0; j < 4; ++j) {
    float a = (float)v1[2 * j], b = (float)v1[2 * j + 1];
    o1[2 * j]     = (bf16)(a * cc[4 + j] - b * ss[4 + j]);
    o1[2 * j + 1] = (bf16)(a * ss[4 + j] + b * cc[4 + j]);
  }
  *(bf16x8*)ptr = o0;
  *(bf16x8*)(ptr + 8) = o1;
}

// ---------------- Flash attention, causal GQA, balanced + prefetched ----------------
// grid (16, NH, B); block = 8 waves (512 thr).
// Waves 0-3 own q-strip qpair (16 rows each), waves 4-7 own strip 31-qpair.
// Every block does exactly 33 compute-tiles -> uniform makespan.
// Double-buffered K (global_load_lds) + V (reg-gather), ONE barrier per kv-tile.
__global__ __launch_bounds__(512) void attn_kernel(const bf16* __restrict__ qkv,
                                                   bf16* __restrict__ y) {
  const int qpair = blockIdx.x, h = blockIdx.y, b = blockIdx.z;
  const int g = h >> 2;  // kv head
  const int tid = threadIdx.x, lane = tid & 63, wave = tid >> 6;
  const int l15 = lane & 15, l4 = lane >> 4;
  const int strip = (wave < 4) ? qpair : (31 - qpair);
  const int w4 = wave & 3;

  __shared__ __attribute__((aligned(16))) bf16 Kb[2][64 * 64];   // [kv][d], swizzled
  __shared__ __attribute__((aligned(16))) bf16 VTs[2][64 * 64];  // [d][kv], swizzled
  __shared__ __attribute__((aligned(16))) bf16 Pb[8][16 * 64];   // per-wave [q][kv], swizzled

  constexpr float SCALE2 = 0.125f * 1.44269504088896f;  // scale * log2(e)

  // Q fragments: rows strip*64 + w4*16 + l15
  bf16x8 qf[2];
  {
    size_t qrow = (size_t)b * T_SEQ + strip * 64 + w4 * 16 + l15;
    const bf16* qp = qkv + qrow * QKV_N + h * HD + l4 * 8;
    qf[0] = *(const bf16x8*)(qp);
    qf[1] = *(const bf16x8*)(qp + 32);
  }

  f32x4 oacc[4] = {};
  float m_run[4], l_run[4];
  #pragma unroll
  for (int r = 0; r < 4; ++r) { m_run[r] = -INFINITY; l_run[r] = 0.f; }

  const int qg0 = strip * 64 + w4 * 16 + l4 * 4;
  const int nt = 32 - qpair;                     // tiles needed by the hi strip
  const size_t kvbase = (size_t)b * T_SEQ;

  const int sr = tid >> 3, sc8 = (tid & 7) << 3;
  const int scsrc = sc8 ^ ((sr & 7) << 3);       // pre-swizzled K source col

  // ---- prologue: stage tile 0 into buffer 0 ----
  {
    __builtin_amdgcn_global_load_lds(
        (const __attribute__((address_space(1))) unsigned int*)
            (qkv + (kvbase + sr) * QKV_N + DIM + g * HD + scsrc),
        (__attribute__((address_space(3))) unsigned int*)(&Kb[0][0] + tid * 8), 16, 0, 0);
    const bf16* vp = qkv + (kvbase + wave * 8) * QKV_N + DIM + NKV * HD + g * HD + lane;
    bf16x8 vr;
    #pragma unroll
    for (int j = 0; j < 8; ++j) vr[j] = vp[(size_t)j * QKV_N];
    *(bf16x8*)((char*)&VTs[0][0] + ((lane * 128 + wave * 16) ^ ((lane & 7) << 4))) = vr;
    asm volatile("s_waitcnt vmcnt(0)" ::: "memory");
    __syncthreads();
  }

  int cur = 0;
  for (int kt = 0; kt < nt; ++kt) {
    const bool has_next = (kt + 1) < nt;
    bf16x8 vr;
    if (has_next) {
      // issue next K tile (async -> LDS) and next V tile (-> regs)
      __builtin_amdgcn_global_load_lds(
          (const __attribute__((address_space(1))) unsigned int*)
              (qkv + (kvbase + (kt + 1) * 64 + sr) * QKV_N + DIM + g * HD + scsrc),
          (__attribute__((address_space(3))) unsigned int*)(&Kb[cur ^ 1][0] + tid * 8), 16, 0, 0);
      const bf16* vp = qkv + (kvbase + (kt + 1) * 64 + wave * 8) * QKV_N
                           + DIM + NKV * HD + g * HD + lane;
      #pragma unroll
      for (int j = 0; j < 8; ++j) vr[j] = vp[(size_t)j * QKV_N];
    }

    if (kt <= strip) {   // this wave's strip still needs this kv tile
      const bf16* kb = &Kb[cur][0];
      const bf16* vt = &VTs[cur][0];
      // ---- S = Q K^T ----
      f32x4 sv[4];
      #pragma unroll
      for (int nt4 = 0; nt4 < 4; ++nt4) {
        f32x4 z = {};
        #pragma unroll
        for (int kk = 0; kk < 2; ++kk) {
          bf16x8 kf = *(const bf16x8*)((const char*)kb +
              (((nt4 * 16 + l15) * 128 + (kk * 32 + l4 * 8) * 2) ^ ((l15 & 7) << 4)));
          z = __builtin_amdgcn_mfma_f32_16x16x32_bf16(qf[kk], kf, z, 0, 0, 0);
        }
        sv[nt4] = z;
      }

      // ---- scale (+ causal mask only on the diagonal tile) ----
      float s[4][4];
      if (kt == strip) {
        #pragma unroll
        for (int nt4 = 0; nt4 < 4; ++nt4) {
          int kg = kt * 64 + nt4 * 16 + l15;
          #pragma unroll
          for (int r = 0; r < 4; ++r) {
            float v = sv[nt4][r] * SCALE2;
            s[nt4][r] = (kg > qg0 + r) ? -INFINITY : v;
          }
        }
      } else {
        #pragma unroll
        for (int nt4 = 0; nt4 < 4; ++nt4)
          #pragma unroll
          for (int r = 0; r < 4; ++r) s[nt4][r] = sv[nt4][r] * SCALE2;
      }

      // ---- online softmax (exp2 domain; row spans 16 lanes) ----
      #pragma unroll
      for (int r = 0; r < 4; ++r) {
        float v = fmaxf(fmaxf(s[0][r], s[1][r]), fmaxf(s[2][r], s[3][r]));
        v = fmaxf(v, __shfl_xor(v, 1));
        v = fmaxf(v, __shfl_xor(v, 2));
        v = fmaxf(v, __shfl_xor(v, 4));
        v = fmaxf(v, __shfl_xor(v, 8));
        float mnew = fmaxf(m_run[r], v);
        float alpha = __builtin_amdgcn_exp2f(m_run[r] - mnew);
        m_run[r] = mnew;
        l_run[r] *= alpha;
        oacc[0][r] *= alpha; oacc[1][r] *= alpha; oacc[2][r] *= alpha; oacc[3][r] *= alpha;
      }

      // ---- P = exp2(s-m) -> per-wave swizzled LDS; row sums ----
      bf16* pb = &Pb[wave][0];
      float psum[4] = {0.f, 0.f, 0.f, 0.f};
      #pragma unroll
      for (int nt4 = 0; nt4 < 4; ++nt4)
        #pragma unroll
        for (int r = 0; r < 4; ++r) {
          float p = __builtin_amdgcn_exp2f(s[nt4][r] - m_run[r]);
          psum[r] += p;
          int row = l4 * 4 + r;
          *(bf16*)((char*)pb + ((row * 128 + (nt4 * 16 + l15) * 2) ^ ((row & 7) << 4))) = (bf16)p;
        }
      #pragma unroll
      for (int r = 0; r < 4; ++r) {
        float v = psum[r];
        v += __shfl_xor(v, 1); v += __shfl_xor(v, 2);
        v += __shfl_xor(v, 4); v += __shfl_xor(v, 8);
        l_run[r] += v;
      }

      // ---- O += P @ V ----
      #pragma unroll
      for (int kk = 0; kk < 2; ++kk) {
        bf16x8 pf = *(const bf16x8*)((const char*)pb +
            ((l15 * 128 + (kk * 32 + l4 * 8) * 2) ^ ((l15 & 7) << 4)));
        #pragma unroll
        for (int dt = 0; dt < 4; ++dt) {
          bf16x8 vf = *(const bf16x8*)((const char*)vt +
              (((dt * 16 + l15) * 128 + (kk * 32 + l4 * 8) * 2) ^ ((l15 & 7) << 4)));
          oacc[dt] = __builtin_amdgcn_mfma_f32_16x16x32_bf16(pf, vf, oacc[dt], 0, 0, 0);
        }
      }
    }

    if (has_next) {
      // V regs -> next LDS buffer (safe: last readers of buf cur^1 were
      // barrier-separated at iteration kt-1); then drain K glds, one barrier.
      *(bf16x8*)((char*)&VTs[cur ^ 1][0] + ((lane * 128 + wave * 16) ^ ((lane & 7) << 4))) = vr;
      asm volatile("s_waitcnt vmcnt(0)" ::: "memory");
      __syncthreads();
      cur ^= 1;
    }
  }

  // ---- epilogue ----
  #pragma unroll
  for (int dt = 0; dt < 4; ++dt)
    #pragma unroll
    for (int r = 0; r < 4; ++r) {
      float v = oacc[dt][r] / l_run[r];
      y[((size_t)b * T_SEQ + strip * 64 + w4 * 16 + l4 * 4 + r) * DIM + h * HD + dt * 16 + l15] = (bf16)v;
    }
}

// ---------------- launch ----------------
extern "C" void kernel_launch(void* const* d_in, const int* in_sizes, int n_in,
                              void* d_out, int out_size, void* d_ws, size_t ws_size,
                              hipStream_t stream) {
  const float* x    = (const float*)d_in[0];
  const float* cosb = (const float*)d_in[1];
  const float* sinb = (const float*)d_in[2];
  const float* wq   = (const float*)d_in[3];
  const float* wk   = (const float*)d_in[4];
  const float* wv   = (const float*)d_in[5];
  const float* wo   = (const float*)d_in[6];
  float* out = (float*)d_out;

  bf16* xb   = (bf16*)d_ws;                           // 4096*2048
  bf16* wqkv = xb + (size_t)MROWS * DIM;              // 3072*2048
  bf16* wob  = wqkv + (size_t)QKV_N * DIM;            // 2048*2048
  bf16* qkv  = wob + (size_t)DIM * DIM;               // 4096*3072
  bf16* y    = qkv + (size_t)MROWS * QKV_N;           // 4096*2048

  cast_kernel<<<2048, 256, 0, stream>>>(x, xb, MROWS * DIM);
  cast_kernel<<<2048, 256, 0, stream>>>(wq, wqkv, DIM * DIM);
  cast_kernel<<<512, 256, 0, stream>>>(wk, wqkv + (size_t)DIM * DIM, NKV * HD * DIM);
  cast_kernel<<<512, 256, 0, stream>>>(wv, wqkv + (size_t)(DIM + NKV * HD) * DIM, NKV * HD * DIM);
  cast_kernel<<<2048, 256, 0, stream>>>(wo, wob, DIM * DIM);

  // QKV projection: M=4096, N=3072, K=2048
  gemm_bt<bf16><<<dim3(MROWS / 128, QKV_N / 128), 256, 0, stream>>>(xb, wqkv, qkv, MROWS, QKV_N, DIM);

  // RoPE on q,k
  rope_kernel<<<(MROWS * 160) / 256, 256, 0, stream>>>(qkv, cosb, sinb);

  // attention: balanced strip pairs
  attn_kernel<<<dim3(16, NH, 2), 512, 0, stream>>>(qkv, y);

  // output projection: M=4096, N=2048, K=2048, f32 out
  gemm_bt<float><<<dim3(MROWS / 128, DIM / 128), 256, 0, stream>>>(y, wob, out, MROWS, DIM, DIM);
}